// Round 2
// baseline (2199.886 us; speedup 1.0000x reference)
//
#include <hip/hip_runtime.h>
#include <cstdint>
#include <cstdio>

#define B_   8
#define L_   4096
#define DM_  1024
#define H_   16
#define D_   64
#define U_   45
#define BH_  (B_*H_)
#define ML_  (B_*L_)

using f32x4  = __attribute__((ext_vector_type(4))) float;
using short8 = __attribute__((ext_vector_type(8))) short;

__device__ __forceinline__ unsigned short f2bf(float f) {
  uint32_t u = __float_as_uint(f);
  u += 0x7fffu + ((u >> 16) & 1u);      // RNE; inputs finite
  return (unsigned short)(u >> 16);
}
__device__ __forceinline__ float bf2f(unsigned short h) {
  return __uint_as_float(((uint32_t)h) << 16);
}

__device__ __forceinline__ void gload16(const void* g, void* l) {
  __builtin_amdgcn_global_load_lds((const __attribute__((address_space(1))) void*)g,
                                   (__attribute__((address_space(3))) void*)l,
                                   16, 0, 0);
}

// ---------------- split fp32 -> bf16 hi/lo ----------------
__global__ __launch_bounds__(256) void split_x(const float* __restrict__ X,
                                               unsigned short* __restrict__ Xh,
                                               unsigned short* __restrict__ Xl, int n4) {
  int i = blockIdx.x * 256 + threadIdx.x;
  const int stride = gridDim.x * 256;
  for (; i < n4; i += stride) {
    const float4 v = ((const float4*)X)[i];
    ushort4 hv, lv;
    hv.x = f2bf(v.x); lv.x = f2bf(v.x - bf2f(hv.x));
    hv.y = f2bf(v.y); lv.y = f2bf(v.y - bf2f(hv.y));
    hv.z = f2bf(v.z); lv.z = f2bf(v.z - bf2f(hv.z));
    hv.w = f2bf(v.w); lv.w = f2bf(v.w - bf2f(hv.w));
    ((ushort4*)Xh)[i] = hv;
    ((ushort4*)Xl)[i] = lv;
  }
}

// W (K x N, row-major) -> W^T hi/lo (N x K, row-major)
__global__ __launch_bounds__(256) void split_wT(const float* __restrict__ W,
                                                unsigned short* __restrict__ WTh,
                                                unsigned short* __restrict__ WTl) {
  const int idx = blockIdx.x * 256 + threadIdx.x;   // 1M threads
  const int n = idx >> 10, k = idx & 1023;
  const float v = W[k * 1024 + n];
  const unsigned short h = f2bf(v);
  WTh[idx] = h;
  WTl[idx] = f2bf(v - bf2f(h));
}

// ---------------- split-bf16 GEMM: C = X*W + bias (fp32 out) ----------------
// A: rows x 1024 (hi/lo), B: W^T 1024x1024 (hi/lo, [n][k]), 128x128 tile, BK=32
template <int NPROD>
__global__ __launch_bounds__(256) void gemm_split(const unsigned short* __restrict__ Agh,
    const unsigned short* __restrict__ Agl, const unsigned short* __restrict__ Bgh,
    const unsigned short* __restrict__ Bgl, const float* __restrict__ bias,
    float* __restrict__ C) {
  constexpr int K = 1024, N = 1024;
  __shared__ unsigned short sA[2][128 * 32];
  __shared__ unsigned short sB[2][128 * 32];
  const int tid = threadIdx.x, wid = tid >> 6, lane = tid & 63;
  const int m0 = blockIdx.y * 128, n0 = blockIdx.x * 128;
  const int wr = wid >> 1, wc = wid & 1;
  const int fr = lane & 15, fq = lane >> 4;
  const int srow = lane >> 2, scol = (lane & 3) * 8;
  f32x4 acc[4][4];
#pragma unroll
  for (int i = 0; i < 4; i++)
#pragma unroll
    for (int j = 0; j < 4; j++) acc[i][j] = f32x4{0.f, 0.f, 0.f, 0.f};

  for (int k0 = 0; k0 < K; k0 += 32) {
#pragma unroll
    for (int c = 0; c < 2; c++) {
      const int ch = wid * 2 + c;            // wave-uniform
      const int row = ch * 16 + srow;
      const size_t ga = (size_t)(m0 + row) * K + (k0 + scol);
      const size_t gb = (size_t)(n0 + row) * K + (k0 + scol);
      gload16(Agh + ga, &sA[0][ch * 512]);
      gload16(Agl + ga, &sA[1][ch * 512]);
      gload16(Bgh + gb, &sB[0][ch * 512]);
      gload16(Bgl + gb, &sB[1][ch * 512]);
    }
    __syncthreads();
    short8 ah[4], al[4], bh[4], bl[4];
#pragma unroll
    for (int i = 0; i < 4; i++) {
      ah[i] = *(const short8*)&sA[0][(wr * 64 + i * 16 + fr) * 32 + fq * 8];
      al[i] = *(const short8*)&sA[1][(wr * 64 + i * 16 + fr) * 32 + fq * 8];
      bh[i] = *(const short8*)&sB[0][(wc * 64 + i * 16 + fr) * 32 + fq * 8];
      bl[i] = *(const short8*)&sB[1][(wc * 64 + i * 16 + fr) * 32 + fq * 8];
    }
#pragma unroll
    for (int i = 0; i < 4; i++)
#pragma unroll
      for (int j = 0; j < 4; j++) {
        acc[i][j] = __builtin_amdgcn_mfma_f32_16x16x32_bf16(ah[i], bh[j], acc[i][j], 0, 0, 0);
        acc[i][j] = __builtin_amdgcn_mfma_f32_16x16x32_bf16(ah[i], bl[j], acc[i][j], 0, 0, 0);
        acc[i][j] = __builtin_amdgcn_mfma_f32_16x16x32_bf16(al[i], bh[j], acc[i][j], 0, 0, 0);
        if (NPROD == 4)
          acc[i][j] = __builtin_amdgcn_mfma_f32_16x16x32_bf16(al[i], bl[j], acc[i][j], 0, 0, 0);
      }
    __syncthreads();
  }
#pragma unroll
  for (int j = 0; j < 4; j++) {
    const int col = n0 + wc * 64 + j * 16 + fr;
    const float bv = bias[col];
#pragma unroll
    for (int i = 0; i < 4; i++) {
      const int row = m0 + wr * 64 + i * 16 + fq * 4;
#pragma unroll
      for (int r = 0; r < 4; r++) C[(size_t)(row + r) * N + col] = acc[i][j][r] + bv;
    }
  }
}

// ---------------- M = max_u(QK_sample) - mean_u(QK_sample), per 2-batch chunk ---
__global__ __launch_bounds__(256) void qk_sample_M(const float* __restrict__ Qc,
    const float* __restrict__ Kf, const int* __restrict__ sidx,
    float* __restrict__ Mout, int b0) {
  const int bloc = blockIdx.x >> 4, h = blockIdx.x & 15;
  const int b = b0 + bloc;
  __shared__ float Ks[U_][68];
  for (int e = threadIdx.x; e < U_ * 64; e += 256) {
    const int u = e >> 6, d = e & 63;
    Ks[u][d] = Kf[((size_t)b * L_ + sidx[u]) * DM_ + h * 64 + d];
  }
  __syncthreads();
  const int l = blockIdx.y * 256 + threadIdx.x;
  const float* qrow = Qc + ((size_t)bloc * L_ + l) * DM_ + h * 64;
  float acc[U_];
#pragma unroll
  for (int u = 0; u < U_; u++) acc[u] = 0.f;
  for (int d4 = 0; d4 < 16; d4++) {
    const float4 q = *(const float4*)&qrow[d4 * 4];
#pragma unroll
    for (int u = 0; u < U_; u++) {
      const float4 kk = *(const float4*)&Ks[u][d4 * 4];
      acc[u] += q.x * kk.x + q.y * kk.y + q.z * kk.z + q.w * kk.w;
    }
  }
  float mx = acc[0], sm = acc[0];
#pragma unroll
  for (int u = 1; u < U_; u++) { mx = fmaxf(mx, acc[u]); sm += acc[u]; }
  Mout[(size_t)(b * 16 + h) * L_ + l] = mx - sm * (1.f / (float)U_);
}

// ---------------- top-45 per (b,h), lower-index tie-break ----------------
__global__ __launch_bounds__(256) void topk45(const float* __restrict__ Mbuf,
                                              int* __restrict__ topidx) {
  const int bh = blockIdx.x, t = threadIdx.x;
  __shared__ float vals[L_];
  __shared__ float rv[256];
  __shared__ int   ri[256];
  for (int i = t; i < L_; i += 256) vals[i] = Mbuf[(size_t)bh * L_ + i];
  __syncthreads();
  for (int it = 0; it < U_; it++) {
    float bv = vals[t * 16]; int bi = t * 16;
#pragma unroll
    for (int jj = 1; jj < 16; jj++) {
      const float v = vals[t * 16 + jj];
      if (v > bv) { bv = v; bi = t * 16 + jj; }
    }
    rv[t] = bv; ri[t] = bi;
    __syncthreads();
    for (int s = 128; s > 0; s >>= 1) {
      if (t < s) {
        if (rv[t + s] > rv[t] || (rv[t + s] == rv[t] && ri[t + s] < ri[t])) {
          rv[t] = rv[t + s]; ri[t] = ri[t + s];
        }
      }
      __syncthreads();
    }
    if (t == 0) { topidx[bh * U_ + it] = ri[0]; vals[ri[0]] = -3.4e38f; }
    __syncthreads();
  }
}

// ---------------- recompute selected Q rows: Qsel[bh][u][64] ----------------
__global__ __launch_bounds__(256) void qsel_k(const float* __restrict__ X,
    const float* __restrict__ Wq, const float* __restrict__ bq,
    const int* __restrict__ topidx, float* __restrict__ Qsel) {
  const int bh = blockIdx.x, b = bh >> 4, h = bh & 15;
  __shared__ float Xs[1024];
  __shared__ float red[256];
  const int t = threadIdx.x, d = t & 63, p = t >> 6;
  for (int u = 0; u < U_; u++) {
    const int l = topidx[bh * U_ + u];
    *(float4*)&Xs[t * 4] = *(const float4*)&X[((size_t)b * L_ + l) * DM_ + t * 4];
    __syncthreads();
    float acc = 0.f;
    const float* wp = Wq + (size_t)(p * 256) * DM_ + h * 64 + d;
    for (int i = 0; i < 256; i++) acc += Xs[p * 256 + i] * wp[(size_t)i * DM_];
    red[t] = acc;
    __syncthreads();
    if (p == 0)
      Qsel[((size_t)bh * U_ + u) * 64 + d] =
          red[d] + red[64 + d] + red[128 + d] + red[192 + d] + bq[h * 64 + d];
    __syncthreads();
  }
}

// ---------------- V mean over L ----------------
__global__ __launch_bounds__(256) void vmean_k(const float* __restrict__ Vf,
                                               float* __restrict__ Vm) {
  const int bh = blockIdx.x, b = bh >> 4, h = bh & 15;
  const int d = threadIdx.x & 63, pp = threadIdx.x >> 6;
  float s = 0.f;
  for (int l = pp; l < L_; l += 4) s += Vf[((size_t)b * L_ + l) * DM_ + h * 64 + d];
  __shared__ float red[256];
  red[threadIdx.x] = s;
  __syncthreads();
  if (pp == 0)
    Vm[bh * 64 + d] = (red[d] + red[64 + d] + red[128 + d] + red[192 + d]) * (1.f / (float)L_);
}

// ---------------- selected-row attention, online softmax, 4-way k-split ----------------
__global__ __launch_bounds__(256) void attn_stage1(const float* __restrict__ Qsel,
    const float* __restrict__ Kf, const float* __restrict__ Vf, float* __restrict__ part) {
  const int bh = blockIdx.x, split = blockIdx.y;
  const int b = bh >> 4, h = bh & 15;
  __shared__ float Qs[48][68];
  __shared__ float Kt[64][68];
  __shared__ float Vt[64][68];
  __shared__ float es[4][64][16];
  for (int e = threadIdx.x; e < 48 * 64; e += 256) {
    const int u = e >> 6, d = e & 63;
    Qs[u][d] = (u < U_) ? Qsel[((size_t)bh * U_ + u) * 64 + d] : 0.f;
  }
  __syncthreads();
  const int wid = threadIdx.x >> 6, lane = threadIdx.x & 63;
  float m[12], S[12], ctx[12];
#pragma unroll
  for (int i = 0; i < 12; i++) { m[i] = -INFINITY; S[i] = 0.f; ctx[i] = 0.f; }
  for (int t = 0; t < 16; t++) {
    const int k0 = split * 1024 + t * 64;
    for (int e = threadIdx.x; e < 64 * 16; e += 256) {
      const int r = e >> 4, c4 = (e & 15) * 4;
      *(float4*)&Kt[r][c4] = *(const float4*)&Kf[((size_t)b * L_ + k0 + r) * DM_ + h * 64 + c4];
      *(float4*)&Vt[r][c4] = *(const float4*)&Vf[((size_t)b * L_ + k0 + r) * DM_ + h * 64 + c4];
    }
    __syncthreads();
    float sc[12];
#pragma unroll
    for (int i = 0; i < 12; i++) sc[i] = 0.f;
    for (int d4 = 0; d4 < 16; d4++) {
      const float4 kk = *(const float4*)&Kt[lane][d4 * 4];
#pragma unroll
      for (int i = 0; i < 12; i++) {
        const float4 q = *(const float4*)&Qs[wid + 4 * i][d4 * 4];
        sc[i] += q.x * kk.x + q.y * kk.y + q.z * kk.z + q.w * kk.w;
      }
    }
#pragma unroll
    for (int i = 0; i < 12; i++) {
      const float s = sc[i] * 0.125f;     // 1/sqrt(64)
      float tm = s;
      for (int off = 32; off > 0; off >>= 1) tm = fmaxf(tm, __shfl_xor(tm, off));
      const float mn = fmaxf(m[i], tm);
      const float f = expf(m[i] - mn);
      const float e = expf(s - mn);
      float sum = e;
      for (int off = 32; off > 0; off >>= 1) sum += __shfl_xor(sum, off);
      S[i] = S[i] * f + sum;
      m[i] = mn;
      ctx[i] *= f;
      es[wid][lane][i] = e;
    }
    for (int k = 0; k < 64; k++) {
      const float v = Vt[k][lane];
      const float4 e0 = *(const float4*)&es[wid][k][0];
      const float4 e1 = *(const float4*)&es[wid][k][4];
      const float4 e2 = *(const float4*)&es[wid][k][8];
      ctx[0] += e0.x * v; ctx[1] += e0.y * v; ctx[2]  += e0.z * v; ctx[3]  += e0.w * v;
      ctx[4] += e1.x * v; ctx[5] += e1.y * v; ctx[6]  += e1.z * v; ctx[7]  += e1.w * v;
      ctx[8] += e2.x * v; ctx[9] += e2.y * v; ctx[10] += e2.z * v; ctx[11] += e2.w * v;
    }
    __syncthreads();
  }
#pragma unroll
  for (int i = 0; i < 12; i++) {
    const int u = wid + 4 * i;
    if (u < U_) {
      float* pb = part + ((size_t)(bh * 4 + split) * U_ + u) * 66;
      if (lane == 0) { pb[0] = m[i]; pb[1] = S[i]; }
      pb[2 + lane] = ctx[i];
    }
  }
}

// combine splits; dctx = ctx_upd - Vmean
__global__ __launch_bounds__(256) void attn_stage2(const float* __restrict__ part,
    const float* __restrict__ Vm, float* __restrict__ dctx) {
  const int bh = blockIdx.x;
  const int wid = threadIdx.x >> 6, lane = threadIdx.x & 63;
  for (int u = wid; u < U_; u += 4) {
    float mm[4], ss[4];
#pragma unroll
    for (int sp = 0; sp < 4; sp++) {
      const float* pb = part + ((size_t)(bh * 4 + sp) * U_ + u) * 66;
      mm[sp] = pb[0]; ss[sp] = pb[1];
    }
    const float M = fmaxf(fmaxf(mm[0], mm[1]), fmaxf(mm[2], mm[3]));
    float Stot = 0.f, c = 0.f;
#pragma unroll
    for (int sp = 0; sp < 4; sp++) {
      const float w = expf(mm[sp] - M);
      Stot += ss[sp] * w;
      c += part[((size_t)(bh * 4 + sp) * U_ + u) * 66 + 2 + lane] * w;
    }
    dctx[((size_t)bh * U_ + u) * 64 + lane] = c / Stot - Vm[bh * 64 + lane];
  }
}

// base[b][:] = concat_h(Vmean) @ Wo + bo
__global__ __launch_bounds__(256) void base_k(const float* __restrict__ Vm,
    const float* __restrict__ Wo, const float* __restrict__ bo, float* __restrict__ base) {
  const int b = blockIdx.y;
  const int j = blockIdx.x * 256 + threadIdx.x;
  float acc = bo[j];
#pragma unroll 8
  for (int i = 0; i < DM_; i++) acc += Vm[b * DM_ + i] * Wo[(size_t)i * DM_ + j];
  base[b * DM_ + j] = acc;
}

// out[b,l,:] = base[b,:]  (broadcast fill; overwrites Kf scratch)
__global__ __launch_bounds__(256) void fill_out(const float* __restrict__ base,
                                                float* __restrict__ out) {
  const size_t g = ((size_t)blockIdx.x * 256 + threadIdx.x) * 4;
  const int b = (int)(g >> 22), j = (int)(g & 1023);
  *(float4*)&out[g] = *(const float4*)&base[(b << 10) + j];
}

// out[b,l,:] += (ctx_upd - Vmean) @ Wo_block[h] for selected rows
__global__ __launch_bounds__(256) void scatter_k(const float* __restrict__ dctx,
    const float* __restrict__ Wo, const int* __restrict__ topidx, float* __restrict__ out) {
  const int bh = blockIdx.x, b = bh >> 4, h = bh & 15;
  __shared__ float dc[U_ * 64];
  __shared__ int topl[U_];
  for (int e = threadIdx.x; e < U_ * 64; e += 256) dc[e] = dctx[(size_t)bh * U_ * 64 + e];
  if (threadIdx.x < U_) topl[threadIdx.x] = topidx[bh * U_ + threadIdx.x];
  __syncthreads();
  const int j4 = threadIdx.x * 4;
  for (int up = 0; up < 6; up++) {
    f32x4 a[8];
#pragma unroll
    for (int i = 0; i < 8; i++) a[i] = f32x4{0.f, 0.f, 0.f, 0.f};
    for (int d = 0; d < 64; d++) {
      const float4 w = *(const float4*)&Wo[(size_t)(h * 64 + d) * DM_ + j4];
#pragma unroll
      for (int i = 0; i < 8; i++) {
        const int u = up * 8 + i;
        if (u < U_) {
          const float cc = dc[u * 64 + d];
          a[i].x += cc * w.x; a[i].y += cc * w.y; a[i].z += cc * w.z; a[i].w += cc * w.w;
        }
      }
    }
#pragma unroll
    for (int i = 0; i < 8; i++) {
      const int u = up * 8 + i;
      if (u < U_) {
        float* row = out + ((size_t)b * L_ + topl[u]) * DM_ + j4;
        atomicAdd(row + 0, a[i].x); atomicAdd(row + 1, a[i].y);
        atomicAdd(row + 2, a[i].z); atomicAdd(row + 3, a[i].w);
      }
    }
  }
}

extern "C" void kernel_launch(void* const* d_in, const int* in_sizes, int n_in,
                              void* d_out, int out_size, void* d_ws, size_t ws_size,
                              hipStream_t stream) {
  const float* queries = (const float*)d_in[0];
  const float* keys    = (const float*)d_in[1];
  const float* values  = (const float*)d_in[2];
  const float* Wq = (const float*)d_in[3]; const float* bq = (const float*)d_in[4];
  const float* Wk = (const float*)d_in[5]; const float* bk = (const float*)d_in[6];
  const float* Wv = (const float*)d_in[7]; const float* bv = (const float*)d_in[8];
  const float* Wo = (const float*)d_in[9]; const float* bo = (const float*)d_in[10];
  const int* sidx = (const int*)d_in[11];

  const size_t LDMsz = (size_t)L_ * DM_;            // 4M elems per batch
  uint8_t* p = (uint8_t*)d_ws;
  auto carve = [&](size_t bytes) { uint8_t* r = p; p += (bytes + 255) & ~(size_t)255; return r; };
  float* Kf = (float*)d_out;                         // K lives in d_out until epilogue
  float* Vf            = (float*)carve((size_t)ML_ * DM_ * 4);      // 134.2 MB
  unsigned short* Xh   = (unsigned short*)carve(2 * LDMsz * 2);     // 16.8 MB
  unsigned short* Xl   = (unsigned short*)carve(2 * LDMsz * 2);     // 16.8 MB
  unsigned short* WTh  = (unsigned short*)carve((size_t)DM_ * DM_ * 2);
  unsigned short* WTl  = (unsigned short*)carve((size_t)DM_ * DM_ * 2);
  float* Qc    = (float*)carve(2 * LDMsz * 4);                      // 33.6 MB
  float* Mbuf  = (float*)carve((size_t)BH_ * L_ * 4);
  int*   topidx = (int*)carve((size_t)BH_ * U_ * 4);
  float* Vm    = (float*)carve((size_t)BH_ * 64 * 4);
  float* Qsel  = (float*)carve((size_t)BH_ * U_ * 64 * 4);
  float* part  = (float*)carve((size_t)BH_ * 4 * U_ * 66 * 4);
  float* dctx  = (float*)carve((size_t)BH_ * U_ * 64 * 4);
  float* base  = (float*)carve((size_t)B_ * DM_ * 4);
  const size_t need = (size_t)(p - (uint8_t*)d_ws);
  if (ws_size < need)
    fprintf(stderr, "ATHENA_WS: need %zu have %zu (WILL FAULT)\n", need, ws_size);

  const int n4chunk = (int)(2 * LDMsz / 4);

  // K projection -> d_out
  split_wT<<<4096, 256, 0, stream>>>(Wk, WTh, WTl);
  for (int c = 0; c < 4; c++) {
    const int b0 = c * 2;
    split_x<<<2048, 256, 0, stream>>>(keys + (size_t)b0 * LDMsz, Xh, Xl, n4chunk);
    gemm_split<4><<<dim3(8, 64), 256, 0, stream>>>(Xh, Xl, WTh, WTl, bk, Kf + (size_t)b0 * LDMsz);
  }
  // V projection -> ws
  split_wT<<<4096, 256, 0, stream>>>(Wv, WTh, WTl);
  for (int c = 0; c < 4; c++) {
    const int b0 = c * 2;
    split_x<<<2048, 256, 0, stream>>>(values + (size_t)b0 * LDMsz, Xh, Xl, n4chunk);
    gemm_split<3><<<dim3(8, 64), 256, 0, stream>>>(Xh, Xl, WTh, WTl, bv, Vf + (size_t)b0 * LDMsz);
  }
  // Q projection (chunked, not materialized) -> M
  split_wT<<<4096, 256, 0, stream>>>(Wq, WTh, WTl);
  for (int c = 0; c < 4; c++) {
    const int b0 = c * 2;
    split_x<<<2048, 256, 0, stream>>>(queries + (size_t)b0 * LDMsz, Xh, Xl, n4chunk);
    gemm_split<4><<<dim3(8, 64), 256, 0, stream>>>(Xh, Xl, WTh, WTl, bq, Qc);
    qk_sample_M<<<dim3(32, L_ / 256), 256, 0, stream>>>(Qc, Kf, sidx, Mbuf, b0);
  }
  topk45<<<BH_, 256, 0, stream>>>(Mbuf, topidx);
  qsel_k<<<BH_, 256, 0, stream>>>(queries, Wq, bq, topidx, Qsel);
  vmean_k<<<BH_, 256, 0, stream>>>(Vf, Vm);
  attn_stage1<<<dim3(BH_, 4), 256, 0, stream>>>(Qsel, Kf, Vf, part);
  attn_stage2<<<BH_, 256, 0, stream>>>(part, Vm, dctx);
  base_k<<<dim3(DM_ / 256, B_), 256, 0, stream>>>(Vm, Wo, bo, base);
  fill_out<<<(int)((size_t)ML_ * DM_ / 4 / 256), 256, 0, stream>>>(base, (float*)d_out);
  scatter_k<<<BH_, 256, 0, stream>>>(dctx, Wo, topidx, (float*)d_out);
}

// Round 3
// 1999.518 us; speedup vs baseline: 1.1002x; 1.1002x over previous
//
#include <hip/hip_runtime.h>
#include <cstdint>
#include <cstdio>

#define B_   8
#define L_   4096
#define DM_  1024
#define H_   16
#define D_   64
#define U_   45
#define BH_  (B_*H_)
#define ML_  (B_*L_)

using f32x4  = __attribute__((ext_vector_type(4))) float;
using short8 = __attribute__((ext_vector_type(8))) short;

__device__ __forceinline__ unsigned short f2bf(float f) {
  uint32_t u = __float_as_uint(f);
  u += 0x7fffu + ((u >> 16) & 1u);      // RNE; inputs finite
  return (unsigned short)(u >> 16);
}
__device__ __forceinline__ float bf2f(unsigned short h) {
  return __uint_as_float(((uint32_t)h) << 16);
}

__device__ __forceinline__ void gload16(const void* g, void* l) {
  __builtin_amdgcn_global_load_lds((const __attribute__((address_space(1))) void*)g,
                                   (__attribute__((address_space(3))) void*)l,
                                   16, 0, 0);
}

// ---------------- split fp32 -> bf16 hi/lo ----------------
__global__ __launch_bounds__(256) void split_x(const float* __restrict__ X,
                                               unsigned short* __restrict__ Xh,
                                               unsigned short* __restrict__ Xl, int n4) {
  int i = blockIdx.x * 256 + threadIdx.x;
  const int stride = gridDim.x * 256;
  for (; i < n4; i += stride) {
    const float4 v = ((const float4*)X)[i];
    ushort4 hv, lv;
    hv.x = f2bf(v.x); lv.x = f2bf(v.x - bf2f(hv.x));
    hv.y = f2bf(v.y); lv.y = f2bf(v.y - bf2f(hv.y));
    hv.z = f2bf(v.z); lv.z = f2bf(v.z - bf2f(hv.z));
    hv.w = f2bf(v.w); lv.w = f2bf(v.w - bf2f(hv.w));
    ((ushort4*)Xh)[i] = hv;
    ((ushort4*)Xl)[i] = lv;
  }
}

// W (K x N, row-major) -> W^T hi/lo (N x K, row-major)
__global__ __launch_bounds__(256) void split_wT(const float* __restrict__ W,
                                                unsigned short* __restrict__ WTh,
                                                unsigned short* __restrict__ WTl) {
  const int idx = blockIdx.x * 256 + threadIdx.x;   // 1M threads
  const int n = idx >> 10, k = idx & 1023;
  const float v = W[k * 1024 + n];
  const unsigned short h = f2bf(v);
  WTh[idx] = h;
  WTl[idx] = f2bf(v - bf2f(h));
}

// ---------------- split-bf16 GEMM: C = X*W + bias (fp32 out) ----------------
template <int NPROD>
__global__ __launch_bounds__(256) void gemm_split(const unsigned short* __restrict__ Agh,
    const unsigned short* __restrict__ Agl, const unsigned short* __restrict__ Bgh,
    const unsigned short* __restrict__ Bgl, const float* __restrict__ bias,
    float* __restrict__ C) {
  constexpr int K = 1024, N = 1024;
  __shared__ unsigned short sA[2][128 * 32];
  __shared__ unsigned short sB[2][128 * 32];
  const int tid = threadIdx.x, wid = tid >> 6, lane = tid & 63;
  const int m0 = blockIdx.y * 128, n0 = blockIdx.x * 128;
  const int wr = wid >> 1, wc = wid & 1;
  const int fr = lane & 15, fq = lane >> 4;
  const int srow = lane >> 2, scol = (lane & 3) * 8;
  f32x4 acc[4][4];
#pragma unroll
  for (int i = 0; i < 4; i++)
#pragma unroll
    for (int j = 0; j < 4; j++) acc[i][j] = f32x4{0.f, 0.f, 0.f, 0.f};

  for (int k0 = 0; k0 < K; k0 += 32) {
#pragma unroll
    for (int c = 0; c < 2; c++) {
      const int ch = wid * 2 + c;            // wave-uniform
      const int row = ch * 16 + srow;
      const size_t ga = (size_t)(m0 + row) * K + (k0 + scol);
      const size_t gb = (size_t)(n0 + row) * K + (k0 + scol);
      gload16(Agh + ga, &sA[0][ch * 512]);
      gload16(Agl + ga, &sA[1][ch * 512]);
      gload16(Bgh + gb, &sB[0][ch * 512]);
      gload16(Bgl + gb, &sB[1][ch * 512]);
    }
    __syncthreads();
    short8 ah[4], al[4], bh[4], bl[4];
#pragma unroll
    for (int i = 0; i < 4; i++) {
      ah[i] = *(const short8*)&sA[0][(wr * 64 + i * 16 + fr) * 32 + fq * 8];
      al[i] = *(const short8*)&sA[1][(wr * 64 + i * 16 + fr) * 32 + fq * 8];
      bh[i] = *(const short8*)&sB[0][(wc * 64 + i * 16 + fr) * 32 + fq * 8];
      bl[i] = *(const short8*)&sB[1][(wc * 64 + i * 16 + fr) * 32 + fq * 8];
    }
#pragma unroll
    for (int i = 0; i < 4; i++)
#pragma unroll
      for (int j = 0; j < 4; j++) {
        acc[i][j] = __builtin_amdgcn_mfma_f32_16x16x32_bf16(ah[i], bh[j], acc[i][j], 0, 0, 0);
        acc[i][j] = __builtin_amdgcn_mfma_f32_16x16x32_bf16(ah[i], bl[j], acc[i][j], 0, 0, 0);
        acc[i][j] = __builtin_amdgcn_mfma_f32_16x16x32_bf16(al[i], bh[j], acc[i][j], 0, 0, 0);
        if (NPROD == 4)
          acc[i][j] = __builtin_amdgcn_mfma_f32_16x16x32_bf16(al[i], bl[j], acc[i][j], 0, 0, 0);
      }
    __syncthreads();
  }
#pragma unroll
  for (int j = 0; j < 4; j++) {
    const int col = n0 + wc * 64 + j * 16 + fr;
    const float bv = bias[col];
#pragma unroll
    for (int i = 0; i < 4; i++) {
      const int row = m0 + wr * 64 + i * 16 + fq * 4;
#pragma unroll
      for (int r = 0; r < 4; r++) C[(size_t)(row + r) * N + col] = acc[i][j][r] + bv;
    }
  }
}

// ---------------- exact fp32 sampled-K rows: Ksamp[bh][u][64] ----------------
__global__ __launch_bounds__(256) void ksel_k(const float* __restrict__ X,
    const float* __restrict__ Wk, const float* __restrict__ bk,
    const int* __restrict__ sidx, float* __restrict__ Ksamp) {
  const int bh = blockIdx.x, b = bh >> 4, h = bh & 15;
  __shared__ float Xs[1024];
  __shared__ float red[256];
  const int t = threadIdx.x, d = t & 63, p = t >> 6;
  for (int u = 0; u < U_; u++) {
    const int l = sidx[u];
    *(float4*)&Xs[t * 4] = *(const float4*)&X[((size_t)b * L_ + l) * DM_ + t * 4];
    __syncthreads();
    float acc = 0.f;
    const float* wp = Wk + (size_t)(p * 256) * DM_ + h * 64 + d;
    for (int i = 0; i < 256; i++) acc += Xs[p * 256 + i] * wp[(size_t)i * DM_];
    red[t] = acc;
    __syncthreads();
    if (p == 0)
      Ksamp[((size_t)bh * U_ + u) * 64 + d] =
          red[d] + red[64 + d] + red[128 + d] + red[192 + d] + bk[h * 64 + d];
    __syncthreads();
  }
}

// ---------------- M = max_u(QK_sample) - mean_u, coalesced Q via LDS ----------------
__global__ __launch_bounds__(256) void qk_sample_M(const float* __restrict__ Qc,
    const float* __restrict__ Ksamp, float* __restrict__ Mout, int b0) {
  const int bloc = blockIdx.x >> 4, h = blockIdx.x & 15;
  const int b = b0 + bloc;
  const int bh = b * 16 + h;
  __shared__ float Qs[256][65];   // stride 65: conflict-free scalar reads
  __shared__ float Ks[U_][68];    // broadcast f4 reads
  for (int e = threadIdx.x; e < U_ * 64; e += 256) {
    const int u = e >> 6, d = e & 63;
    Ks[u][d] = Ksamp[((size_t)bh * U_ + u) * 64 + d];
  }
  const int l0 = blockIdx.y * 256;
  for (int e = threadIdx.x; e < 256 * 64; e += 256) {
    const int r = e >> 6, d = e & 63;
    Qs[r][d] = Qc[((size_t)bloc * L_ + l0 + r) * DM_ + h * 64 + d];
  }
  __syncthreads();
  const int t = threadIdx.x;
  float acc[U_];
#pragma unroll
  for (int u = 0; u < U_; u++) acc[u] = 0.f;
  for (int d = 0; d < 64; d += 4) {
    const float q0 = Qs[t][d], q1 = Qs[t][d + 1], q2 = Qs[t][d + 2], q3 = Qs[t][d + 3];
#pragma unroll
    for (int u = 0; u < U_; u++) {
      const float4 kk = *(const float4*)&Ks[u][d];
      acc[u] += q0 * kk.x + q1 * kk.y + q2 * kk.z + q3 * kk.w;
    }
  }
  float mx = acc[0], sm = acc[0];
#pragma unroll
  for (int u = 1; u < U_; u++) { mx = fmaxf(mx, acc[u]); sm += acc[u]; }
  Mout[(size_t)bh * L_ + l0 + t] = mx - sm * (1.f / (float)U_);
}

// ---------------- top-45 per (b,h), lower-index tie-break ----------------
__global__ __launch_bounds__(256) void topk45(const float* __restrict__ Mbuf,
                                              int* __restrict__ topidx) {
  const int bh = blockIdx.x, t = threadIdx.x;
  __shared__ float vals[L_];
  __shared__ float rv[256];
  __shared__ int   ri[256];
  for (int i = t; i < L_; i += 256) vals[i] = Mbuf[(size_t)bh * L_ + i];
  __syncthreads();
  for (int it = 0; it < U_; it++) {
    float bv = vals[t * 16]; int bi = t * 16;
#pragma unroll
    for (int jj = 1; jj < 16; jj++) {
      const float v = vals[t * 16 + jj];
      if (v > bv) { bv = v; bi = t * 16 + jj; }
    }
    rv[t] = bv; ri[t] = bi;
    __syncthreads();
    for (int s = 128; s > 0; s >>= 1) {
      if (t < s) {
        if (rv[t + s] > rv[t] || (rv[t + s] == rv[t] && ri[t + s] < ri[t])) {
          rv[t] = rv[t + s]; ri[t] = ri[t + s];
        }
      }
      __syncthreads();
    }
    if (t == 0) { topidx[bh * U_ + it] = ri[0]; vals[ri[0]] = -3.4e38f; }
    __syncthreads();
  }
}

// ---------------- recompute selected Q rows: Qsel[bh][u][64] ----------------
__global__ __launch_bounds__(256) void qsel_k(const float* __restrict__ X,
    const float* __restrict__ Wq, const float* __restrict__ bq,
    const int* __restrict__ topidx, float* __restrict__ Qsel) {
  const int bh = blockIdx.x, b = bh >> 4, h = bh & 15;
  __shared__ float Xs[1024];
  __shared__ float red[256];
  const int t = threadIdx.x, d = t & 63, p = t >> 6;
  for (int u = 0; u < U_; u++) {
    const int l = topidx[bh * U_ + u];
    *(float4*)&Xs[t * 4] = *(const float4*)&X[((size_t)b * L_ + l) * DM_ + t * 4];
    __syncthreads();
    float acc = 0.f;
    const float* wp = Wq + (size_t)(p * 256) * DM_ + h * 64 + d;
    for (int i = 0; i < 256; i++) acc += Xs[p * 256 + i] * wp[(size_t)i * DM_];
    red[t] = acc;
    __syncthreads();
    if (p == 0)
      Qsel[((size_t)bh * U_ + u) * 64 + d] =
          red[d] + red[64 + d] + red[128 + d] + red[192 + d] + bq[h * 64 + d];
    __syncthreads();
  }
}

// ---------------- V mean: two-phase deterministic ----------------
__global__ __launch_bounds__(256) void vmean_partial(const float* __restrict__ Vf,
                                                     float* __restrict__ partial) {
  const int col = blockIdx.x * 256 + threadIdx.x;
  const int s = blockIdx.y, b = blockIdx.z;
  const float* src = Vf + ((size_t)b * L_ + s * 64) * DM_ + col;
  float acc = 0.f;
#pragma unroll 8
  for (int l = 0; l < 64; l++) acc += src[(size_t)l * DM_];
  partial[((size_t)b * 64 + s) * DM_ + col] = acc;
}
__global__ __launch_bounds__(256) void vmean_combine(const float* __restrict__ partial,
                                                     float* __restrict__ Vm) {
  const int idx = blockIdx.x * 256 + threadIdx.x;  // 8192 = B_*DM_
  const int b = idx >> 10, col = idx & 1023;
  float acc = 0.f;
  for (int s = 0; s < 64; s++) acc += partial[((size_t)b * 64 + s) * DM_ + col];
  Vm[idx] = acc * (1.f / (float)L_);
}

// ---------------- selected-row attention, online softmax, 4-way k-split ----------------
__global__ __launch_bounds__(256) void attn_stage1(const float* __restrict__ Qsel,
    const float* __restrict__ Kf, const float* __restrict__ Vf, float* __restrict__ part) {
  const int bh = blockIdx.x, split = blockIdx.y;
  const int b = bh >> 4, h = bh & 15;
  __shared__ float Qs[48][68];
  __shared__ float Kt[64][68];
  __shared__ float Vt[64][68];
  __shared__ float es[4][64][16];
  for (int e = threadIdx.x; e < 48 * 64; e += 256) {
    const int u = e >> 6, d = e & 63;
    Qs[u][d] = (u < U_) ? Qsel[((size_t)bh * U_ + u) * 64 + d] : 0.f;
  }
  __syncthreads();
  const int wid = threadIdx.x >> 6, lane = threadIdx.x & 63;
  float m[12], S[12], ctx[12];
#pragma unroll
  for (int i = 0; i < 12; i++) { m[i] = -INFINITY; S[i] = 0.f; ctx[i] = 0.f; }
  for (int t = 0; t < 16; t++) {
    const int k0 = split * 1024 + t * 64;
    for (int e = threadIdx.x; e < 64 * 16; e += 256) {
      const int r = e >> 4, c4 = (e & 15) * 4;
      *(float4*)&Kt[r][c4] = *(const float4*)&Kf[((size_t)b * L_ + k0 + r) * DM_ + h * 64 + c4];
      *(float4*)&Vt[r][c4] = *(const float4*)&Vf[((size_t)b * L_ + k0 + r) * DM_ + h * 64 + c4];
    }
    __syncthreads();
    float sc[12];
#pragma unroll
    for (int i = 0; i < 12; i++) sc[i] = 0.f;
    for (int d4 = 0; d4 < 16; d4++) {
      const float4 kk = *(const float4*)&Kt[lane][d4 * 4];
#pragma unroll
      for (int i = 0; i < 12; i++) {
        const float4 q = *(const float4*)&Qs[wid + 4 * i][d4 * 4];
        sc[i] += q.x * kk.x + q.y * kk.y + q.z * kk.z + q.w * kk.w;
      }
    }
#pragma unroll
    for (int i = 0; i < 12; i++) {
      const float s = sc[i] * 0.125f;     // 1/sqrt(64)
      float tm = s;
      for (int off = 32; off > 0; off >>= 1) tm = fmaxf(tm, __shfl_xor(tm, off));
      const float mn = fmaxf(m[i], tm);
      const float f = expf(m[i] - mn);
      const float e = expf(s - mn);
      float sum = e;
      for (int off = 32; off > 0; off >>= 1) sum += __shfl_xor(sum, off);
      S[i] = S[i] * f + sum;
      m[i] = mn;
      ctx[i] *= f;
      es[wid][lane][i] = e;
    }
    for (int k = 0; k < 64; k++) {
      const float v = Vt[k][lane];
      const float4 e0 = *(const float4*)&es[wid][k][0];
      const float4 e1 = *(const float4*)&es[wid][k][4];
      const float4 e2 = *(const float4*)&es[wid][k][8];
      ctx[0] += e0.x * v; ctx[1] += e0.y * v; ctx[2]  += e0.z * v; ctx[3]  += e0.w * v;
      ctx[4] += e1.x * v; ctx[5] += e1.y * v; ctx[6]  += e1.z * v; ctx[7]  += e1.w * v;
      ctx[8] += e2.x * v; ctx[9] += e2.y * v; ctx[10] += e2.z * v; ctx[11] += e2.w * v;
    }
    __syncthreads();
  }
#pragma unroll
  for (int i = 0; i < 12; i++) {
    const int u = wid + 4 * i;
    if (u < U_) {
      float* pb = part + ((size_t)(bh * 4 + split) * U_ + u) * 66;
      if (lane == 0) { pb[0] = m[i]; pb[1] = S[i]; }
      pb[2 + lane] = ctx[i];
    }
  }
}

// combine splits; dctx = ctx_upd - Vmean
__global__ __launch_bounds__(256) void attn_stage2(const float* __restrict__ part,
    const float* __restrict__ Vm, float* __restrict__ dctx) {
  const int bh = blockIdx.x;
  const int wid = threadIdx.x >> 6, lane = threadIdx.x & 63;
  for (int u = wid; u < U_; u += 4) {
    float mm[4], ss[4];
#pragma unroll
    for (int sp = 0; sp < 4; sp++) {
      const float* pb = part + ((size_t)(bh * 4 + sp) * U_ + u) * 66;
      mm[sp] = pb[0]; ss[sp] = pb[1];
    }
    const float M = fmaxf(fmaxf(mm[0], mm[1]), fmaxf(mm[2], mm[3]));
    float Stot = 0.f, c = 0.f;
#pragma unroll
    for (int sp = 0; sp < 4; sp++) {
      const float w = expf(mm[sp] - M);
      Stot += ss[sp] * w;
      c += part[((size_t)(bh * 4 + sp) * U_ + u) * 66 + 2 + lane] * w;
    }
    dctx[((size_t)bh * U_ + u) * 64 + lane] = c / Stot - Vm[bh * 64 + lane];
  }
}

// base[b][:] = concat_h(Vmean) @ Wo + bo
__global__ __launch_bounds__(256) void base_k(const float* __restrict__ Vm,
    const float* __restrict__ Wo, const float* __restrict__ bo, float* __restrict__ base) {
  const int b = blockIdx.y;
  const int j = blockIdx.x * 256 + threadIdx.x;
  float acc = bo[j];
#pragma unroll 8
  for (int i = 0; i < DM_; i++) acc += Vm[b * DM_ + i] * Wo[(size_t)i * DM_ + j];
  base[b * DM_ + j] = acc;
}

// out[b,l,:] = base[b,:]  (broadcast fill; overwrites Kf scratch)
__global__ __launch_bounds__(256) void fill_out(const float* __restrict__ base,
                                                float* __restrict__ out) {
  const size_t g = ((size_t)blockIdx.x * 256 + threadIdx.x) * 4;
  const int b = (int)(g >> 22), j = (int)(g & 1023);
  *(float4*)&out[g] = *(const float4*)&base[(b << 10) + j];
}

// out[b,l,:] += (ctx_upd - Vmean) @ Wo_block[h] for selected rows
__global__ __launch_bounds__(256) void scatter_k(const float* __restrict__ dctx,
    const float* __restrict__ Wo, const int* __restrict__ topidx, float* __restrict__ out) {
  const int bh = blockIdx.x, b = bh >> 4, h = bh & 15;
  __shared__ float dc[U_ * 64];
  __shared__ int topl[U_];
  for (int e = threadIdx.x; e < U_ * 64; e += 256) dc[e] = dctx[(size_t)bh * U_ * 64 + e];
  if (threadIdx.x < U_) topl[threadIdx.x] = topidx[bh * U_ + threadIdx.x];
  __syncthreads();
  const int j4 = threadIdx.x * 4;
  for (int up = 0; up < 6; up++) {
    f32x4 a[8];
#pragma unroll
    for (int i = 0; i < 8; i++) a[i] = f32x4{0.f, 0.f, 0.f, 0.f};
    for (int d = 0; d < 64; d++) {
      const float4 w = *(const float4*)&Wo[(size_t)(h * 64 + d) * DM_ + j4];
#pragma unroll
      for (int i = 0; i < 8; i++) {
        const int u = up * 8 + i;
        if (u < U_) {
          const float cc = dc[u * 64 + d];
          a[i].x += cc * w.x; a[i].y += cc * w.y; a[i].z += cc * w.z; a[i].w += cc * w.w;
        }
      }
    }
#pragma unroll
    for (int i = 0; i < 8; i++) {
      const int u = up * 8 + i;
      if (u < U_) {
        float* row = out + ((size_t)b * L_ + topl[u]) * DM_ + j4;
        atomicAdd(row + 0, a[i].x); atomicAdd(row + 1, a[i].y);
        atomicAdd(row + 2, a[i].z); atomicAdd(row + 3, a[i].w);
      }
    }
  }
}

extern "C" void kernel_launch(void* const* d_in, const int* in_sizes, int n_in,
                              void* d_out, int out_size, void* d_ws, size_t ws_size,
                              hipStream_t stream) {
  const float* queries = (const float*)d_in[0];
  const float* keys    = (const float*)d_in[1];
  const float* values  = (const float*)d_in[2];
  const float* Wq = (const float*)d_in[3]; const float* bq = (const float*)d_in[4];
  const float* Wk = (const float*)d_in[5]; const float* bk = (const float*)d_in[6];
  const float* Wv = (const float*)d_in[7]; const float* bv = (const float*)d_in[8];
  const float* Wo = (const float*)d_in[9]; const float* bo = (const float*)d_in[10];
  const int* sidx = (const int*)d_in[11];

  const size_t LDMsz = (size_t)L_ * DM_;            // 4M elems per batch
  uint8_t* p = (uint8_t*)d_ws;
  auto carve = [&](size_t bytes) { uint8_t* r = p; p += (bytes + 255) & ~(size_t)255; return r; };
  float* Kf = (float*)d_out;                         // K lives in d_out until epilogue
  float* Vf            = (float*)carve((size_t)ML_ * DM_ * 4);      // 134.2 MB
  unsigned short* Xh   = (unsigned short*)carve(2 * LDMsz * 2);     // 16.8 MB
  unsigned short* Xl   = (unsigned short*)carve(2 * LDMsz * 2);     // 16.8 MB
  unsigned short* WTh  = (unsigned short*)carve((size_t)DM_ * DM_ * 2);
  unsigned short* WTl  = (unsigned short*)carve((size_t)DM_ * DM_ * 2);
  float* Qc    = (float*)carve(2 * LDMsz * 4);                      // 33.6 MB
  float* Mbuf  = (float*)carve((size_t)BH_ * L_ * 4);
  int*   topidx = (int*)carve((size_t)BH_ * U_ * 4);
  float* Vm    = (float*)carve((size_t)BH_ * 64 * 4);
  float* Qsel  = (float*)carve((size_t)BH_ * U_ * 64 * 4);
  float* Ksamp = (float*)carve((size_t)BH_ * U_ * 64 * 4);
  float* part  = (float*)carve((size_t)BH_ * 4 * U_ * 66 * 4);
  float* dctx  = (float*)carve((size_t)BH_ * U_ * 64 * 4);
  float* base  = (float*)carve((size_t)B_ * DM_ * 4);
  float* vpart = (float*)carve((size_t)B_ * 64 * DM_ * 4);          // 2 MB
  const size_t need = (size_t)(p - (uint8_t*)d_ws);
  if (ws_size < need)
    fprintf(stderr, "ATHENA_WS: need %zu have %zu (WILL FAULT)\n", need, ws_size);

  const int n4chunk = (int)(2 * LDMsz / 4);

  // exact sampled-K rows (input-only dependency)
  ksel_k<<<BH_, 256, 0, stream>>>(keys, Wk, bk, sidx, Ksamp);

  // K projection -> d_out (NPROD=3: scores tolerate 2^-16 relative; ranking uses Ksamp)
  split_wT<<<4096, 256, 0, stream>>>(Wk, WTh, WTl);
  for (int c = 0; c < 4; c++) {
    const int b0 = c * 2;
    split_x<<<2048, 256, 0, stream>>>(keys + (size_t)b0 * LDMsz, Xh, Xl, n4chunk);
    gemm_split<3><<<dim3(8, 64), 256, 0, stream>>>(Xh, Xl, WTh, WTl, bk, Kf + (size_t)b0 * LDMsz);
  }
  // V projection -> ws
  split_wT<<<4096, 256, 0, stream>>>(Wv, WTh, WTl);
  for (int c = 0; c < 4; c++) {
    const int b0 = c * 2;
    split_x<<<2048, 256, 0, stream>>>(values + (size_t)b0 * LDMsz, Xh, Xl, n4chunk);
    gemm_split<3><<<dim3(8, 64), 256, 0, stream>>>(Xh, Xl, WTh, WTl, bv, Vf + (size_t)b0 * LDMsz);
  }
  // Q projection (chunked, not materialized) -> M (NPROD=4: ranking precision)
  split_wT<<<4096, 256, 0, stream>>>(Wq, WTh, WTl);
  for (int c = 0; c < 4; c++) {
    const int b0 = c * 2;
    split_x<<<2048, 256, 0, stream>>>(queries + (size_t)b0 * LDMsz, Xh, Xl, n4chunk);
    gemm_split<4><<<dim3(8, 64), 256, 0, stream>>>(Xh, Xl, WTh, WTl, bq, Qc);
    qk_sample_M<<<dim3(32, L_ / 256), 256, 0, stream>>>(Qc, Ksamp, Mbuf, b0);
  }
  topk45<<<BH_, 256, 0, stream>>>(Mbuf, topidx);
  qsel_k<<<BH_, 256, 0, stream>>>(queries, Wq, bq, topidx, Qsel);
  vmean_partial<<<dim3(DM_ / 256, 64, B_), 256, 0, stream>>>(Vf, vpart);
  vmean_combine<<<(B_ * DM_) / 256, 256, 0, stream>>>(vpart, Vm);
  attn_stage1<<<dim3(BH_, 4), 256, 0, stream>>>(Qsel, Kf, Vf, part);
  attn_stage2<<<BH_, 256, 0, stream>>>(part, Vm, dctx);
  base_k<<<dim3(DM_ / 256, B_), 256, 0, stream>>>(Vm, Wo, bo, base);
  fill_out<<<(int)((size_t)ML_ * DM_ / 4 / 256), 256, 0, stream>>>(base, (float*)d_out);
  scatter_k<<<BH_, 256, 0, stream>>>(dctx, Wo, topidx, (float*)d_out);
}